// Round 1
// baseline (783.244 us; speedup 1.0000x reference)
//
#include <hip/hip_runtime.h>

// OnlineDenoisingAutoencoder: LSTM(B=2048, T=2048, in=1, proj=16, H=32)
// R7: gate-split decomposition for 2 waves/SIMD.
// Previous (R6): 2 batches/wave, 4 gates/lane -> 1024 waves = 1/SIMD,
// VALUBusy 69.6%, ~237 stall cyc/step fully exposed (LDS h round-trip +
// transcendental chains). This version: 1 batch/wave, 64 lanes = 2 halves
// x 32 hidden j. Lower half owns gate rows (i,g), upper half (f,o):
//   rA = half*32 + j   (always sigmoid: i or f)
//   rB = 64 + half*32+j (tanh for half0 (g), sigmoid for half1 (o))
// -> 32 fdot2/step/lane (was 64), 2048 waves = 2/SIMD so the per-step
// serial chain overlaps with the sibling wave's issue.
// Cross-half exchange of activations via v_permlane32_swap_b32 (2 VALU ops,
// no LDS, no cndmask): r[0] = lower-half value in both halves (i / g),
// r[1] = upper-half value in both halves (f / o). Both halves compute the
// identical c / tanh(c) / h (replicated), publish h fp16 to their own LDS
// half-buffer, gather with 4x ds_read_b128 (broadcast) as before.
// Output projection: same 5-step DPP reduce; result in lane 31.
// History: R2 LDS-pipe-bound 864us; R3 pk_fma not 2x (996us); R4 readlane
// broadcast 2x modeled VALU (1034us); R6 670us @ 69.6% VALUBusy, 1/SIMD.

#define BB 2048
#define TT 2048
#define HH 32

typedef _Float16 h2 __attribute__((ext_vector_type(2)));
typedef unsigned int uint2v __attribute__((ext_vector_type(2)));

__device__ __forceinline__ float gate_eval(float x, float m, float a, float b) {
    // a * (1 / (1 + 2^(m*x))) + b ; sigmoid: m=-log2e,a=1,b=0 ; tanh: m=-2log2e,a=2,b=-1
    float e = __builtin_amdgcn_exp2f(x * m);
    float r = __builtin_amdgcn_rcpf(1.0f + e);
    return fmaf(a, r, b);
}

template <int CTRL>
__device__ __forceinline__ float dpp_add(float v) {
    int s = __builtin_amdgcn_update_dpp(0, __float_as_int(v), CTRL, 0xf, 0xf, true);
    return v + __int_as_float(s);
}

struct HVec { h2 v[16]; };

__device__ __forceinline__ HVec gather_h(const _Float16* base) {
    const float4* p = (const float4*)base;   // 64 B = 4 x ds_read_b128 (broadcast)
    float4 q0 = p[0], q1 = p[1], q2 = p[2], q3 = p[3];
    HVec r;
    r.v[0]  = __builtin_bit_cast(h2, q0.x); r.v[1]  = __builtin_bit_cast(h2, q0.y);
    r.v[2]  = __builtin_bit_cast(h2, q0.z); r.v[3]  = __builtin_bit_cast(h2, q0.w);
    r.v[4]  = __builtin_bit_cast(h2, q1.x); r.v[5]  = __builtin_bit_cast(h2, q1.y);
    r.v[6]  = __builtin_bit_cast(h2, q1.z); r.v[7]  = __builtin_bit_cast(h2, q1.w);
    r.v[8]  = __builtin_bit_cast(h2, q2.x); r.v[9]  = __builtin_bit_cast(h2, q2.y);
    r.v[10] = __builtin_bit_cast(h2, q2.z); r.v[11] = __builtin_bit_cast(h2, q2.w);
    r.v[12] = __builtin_bit_cast(h2, q3.x); r.v[13] = __builtin_bit_cast(h2, q3.y);
    r.v[14] = __builtin_bit_cast(h2, q3.z); r.v[15] = __builtin_bit_cast(h2, q3.w);
    return r;
}

__global__ __launch_bounds__(256) void lstm_fused_kernel(
    const float* __restrict__ x_seq,  // [B,T,1]
    const float* __restrict__ Wp,     // [16,1]
    const float* __restrict__ bp,     // [16]
    const float* __restrict__ W_ih,   // [128,16]
    const float* __restrict__ W_hh,   // [128,32]
    const float* __restrict__ b_ih,   // [128]
    const float* __restrict__ b_hh,   // [128]
    const float* __restrict__ Wo,     // [1,32]
    const float* __restrict__ bo,     // [1]
    float* __restrict__ out)          // [B,T,1] fp32
{
    const int tid  = threadIdx.x;
    const int wave = tid >> 6;
    const int lane = tid & 63;
    const int half = lane >> 5;      // gate-pair selector: 0 -> (i,g), 1 -> (f,o)
    const int j    = lane & 31;      // hidden index this lane owns
    const int b    = blockIdx.x * 4 + wave;   // one batch element per wave

    // PyTorch gate row order: i=[0,32), f=[32,64), g=[64,96), o=[96,128)
    const int rA = half * HH + j;            // i (half0) or f (half1) -- sigmoid
    const int rB = 2 * HH + half * HH + j;   // g (half0, tanh) or o (half1, sigmoid)

    // ---- W_hh rows (2 gates per lane) into registers as packed fp16 pairs ----
    h2 wA[16], wB[16];
    {
        const float2* pA = (const float2*)(W_hh + rA * HH);
        const float2* pB = (const float2*)(W_hh + rB * HH);
#pragma unroll
        for (int k = 0; k < 16; ++k) {
            float2 a = pA[k], q = pB[k];
            wA[k].x = (_Float16)a.x; wA[k].y = (_Float16)a.y;
            wB[k].x = (_Float16)q.x; wB[k].y = (_Float16)q.y;
        }
    }

    // ---- collapse input pipeline: gate pre-act = dot + x*xA + kA (INPUT_DIM==1) ----
    float xA = 0.f, kA = 0.f, xB = 0.f, kB = 0.f;
#pragma unroll
    for (int p = 0; p < 16; ++p) {
        float wpv = Wp[p], bpv = bp[p];
        float wa = W_ih[rA * 16 + p], wb = W_ih[rB * 16 + p];
        xA = fmaf(wa, wpv, xA);  kA = fmaf(wa, bpv, kA);
        xB = fmaf(wb, wpv, xB);  kB = fmaf(wb, bpv, kB);
    }
    kA += b_ih[rA] + b_hh[rA];
    kB += b_ih[rB] + b_hh[rB];

    const float LOG2E = 1.44269504088896340736f;
    // per-lane gate-B nonlinearity constants: tanh (half0) vs sigmoid (half1)
    const float mB = half ? -LOG2E : -2.0f * LOG2E;
    const float aB = half ? 1.0f   : 2.0f;
    const float bB = half ? 0.0f   : -1.0f;

    const float woj = Wo[j];
    const float bo0 = bo[0];

    // per-(wave,half) h replica, fp16, 64 B each (h identical across halves)
    __shared__ __align__(16) _Float16 hsh[4][2][HH];
    _Float16* hbase = &hsh[wave][half][0];
    hbase[j] = (_Float16)0.0f;

    float c = 0.0f;
    const float* xp = x_seq + (size_t)b * TT;
    float* op = out + (size_t)b * TT;

    HVec hcur = gather_h(hbase);            // zeros (same-wave DS order)
    float4 x4 = *(const float4*)(xp);

    for (int t = 0; t < TT; t += 4) {
        const int tn = (t + 4 < TT) ? (t + 4) : t;
        float4 x4n = *(const float4*)(xp + tn);   // prefetch next group
        float outv[4];
#pragma unroll
        for (int u = 0; u < 4; ++u) {
            float xv = (u == 0) ? x4.x : (u == 1) ? x4.y : (u == 2) ? x4.z : x4.w;

            // 2 gate dots over h (fp16 inputs, fp32 accum), 2 accumulators each
            float sA0 = kA, sA1 = xv * xA;
            float sB0 = kB, sB1 = xv * xB;
#pragma unroll
            for (int k = 0; k < 16; k += 2) {
                h2 h0 = hcur.v[k], h1 = hcur.v[k + 1];
                sA0 = __builtin_amdgcn_fdot2(wA[k],     h0, sA0, false);
                sB0 = __builtin_amdgcn_fdot2(wB[k],     h0, sB0, false);
                sA1 = __builtin_amdgcn_fdot2(wA[k + 1], h1, sA1, false);
                sB1 = __builtin_amdgcn_fdot2(wB[k + 1], h1, sB1, false);
            }

            float Aact = gate_eval(sA0 + sA1, -LOG2E, 1.0f, 0.0f);  // sigmoid(i|f)
            float Bact = gate_eval(sB0 + sB1, mB, aB, bB);          // tanh(g)|sigmoid(o)

            // cross-half all-broadcast: r[0] = lower-half value in both halves,
            // r[1] = upper-half value in both halves (v_permlane32_swap_b32)
            uint2v eA = __builtin_amdgcn_permlane32_swap(
                __float_as_uint(Aact), __float_as_uint(Aact), false, false);
            uint2v eB = __builtin_amdgcn_permlane32_swap(
                __float_as_uint(Bact), __float_as_uint(Bact), false, false);
            float iv = __uint_as_float(eA[0]);   // sigmoid(i)
            float fv = __uint_as_float(eA[1]);   // sigmoid(f)
            float gv = __uint_as_float(eB[0]);   // tanh(g)
            float ov = __uint_as_float(eB[1]);   // sigmoid(o)

            c = fmaf(fv, c, iv * gv);
            float th = gate_eval(c, -2.0f * LOG2E, 2.0f, -1.0f); // tanh(c)
            float h = ov * th;

            // publish h (both halves write identical value to their own replica),
            // then issue next gather; DPP reduce below overlaps the LDS latency
            hbase[j] = (_Float16)h;
            hcur = gather_h(hbase);

            // fused output projection: width-32 reduce on VALU via DPP.
            // row_shr 1/2/4/8 then row_bcast15 -> total lands in lane 31.
            float po = woj * h;
            po = dpp_add<0x111>(po);
            po = dpp_add<0x112>(po);
            po = dpp_add<0x114>(po);
            po = dpp_add<0x118>(po);
            po = dpp_add<0x142>(po);
            outv[u] = po + bo0;
        }
        if (lane == 31) {
            *(float4*)(op + t) = make_float4(outv[0], outv[1], outv[2], outv[3]);
        }
        x4 = x4n;
    }
}

extern "C" void kernel_launch(void* const* d_in, const int* in_sizes, int n_in,
                              void* d_out, int out_size, void* d_ws, size_t ws_size,
                              hipStream_t stream) {
    const float* x_seq = (const float*)d_in[0];
    const float* Wp    = (const float*)d_in[1];
    const float* bp    = (const float*)d_in[2];
    const float* W_ih  = (const float*)d_in[3];
    const float* W_hh  = (const float*)d_in[4];
    const float* b_ih  = (const float*)d_in[5];
    const float* b_hh  = (const float*)d_in[6];
    const float* Wo    = (const float*)d_in[7];
    const float* bo    = (const float*)d_in[8];
    float* out = (float*)d_out;

    dim3 grid(BB / 4);   // 4 waves/block, 1 batch element/wave -> 2048 waves (2/SIMD)
    dim3 block(256);
    lstm_fused_kernel<<<grid, block, 0, stream>>>(
        x_seq, Wp, bp, W_ih, W_hh, b_ih, b_hh, Wo, bo, out);
}

// Round 2
// 734.015 us; speedup vs baseline: 1.0671x; 1.0671x over previous
//
#include <hip/hip_runtime.h>

// OnlineDenoisingAutoencoder: LSTM(B=2048, T=2048, in=1, proj=16, H=32)
// R8 = R6 (2 batches/wave, 4 gates/lane, 1024 waves) with the LDS h-broadcast
// replaced by an in-register DPP/permlane butterfly all-gather (18 VALU ops,
// no memory). R6's 30% stall was dominated by the per-step ds_write ->
// 4x ds_read round trip (~100-120 cyc, un-hideable at 1 wave/SIMD). The
// butterfly delivers all 32 h values to every lane in a lane-dependent slot
// order; W_hh is pre-permuted at init to match by running the IDENTICAL
// DPP/permlane sequence on integer lane indices (robust to rotate-direction
// and permlane element-order conventions). Batch<->lane map is row-parity
// (batch A = rows 0&2, B = rows 1&3) so the cross-row exchange is exactly
// permlane32_swap (lane ^ 32), proven numerically in R7.
// History: R2 LDS-pipe-bound 864us; R3 pk_fma not 2x (996); R4 readlane
// (1034); R6 665us @69.6% busy 1/SIMD; R7 gate-split 796us (fixed-cost
// amortization loss: 348 vs 271 busy-cyc/batch-step).

#define BB 2048
#define TT 2048
#define HH 32

typedef _Float16 h2 __attribute__((ext_vector_type(2)));
typedef unsigned int uint2v __attribute__((ext_vector_type(2)));

__device__ __forceinline__ float gate_eval(float x, float m, float a, float b) {
    // a * (1 / (1 + 2^(m*x))) + b ; sigmoid: m=-log2e,a=1,b=0 ; tanh: m=-2log2e,a=2,b=-1
    float e = __builtin_amdgcn_exp2f(x * m);
    float r = __builtin_amdgcn_rcpf(1.0f + e);
    return fmaf(a, r, b);
}

template <int CTRL>
__device__ __forceinline__ int dpp_i(int v) {
    return __builtin_amdgcn_update_dpp(0, v, CTRL, 0xf, 0xf, true);
}

template <int CTRL>
__device__ __forceinline__ float dpp_add(float v) {
    int s = __builtin_amdgcn_update_dpp(0, __float_as_int(v), CTRL, 0xf, 0xf, true);
    return v + __int_as_float(s);
}

#define DPP_XOR1 0xB1   // quad_perm [1,0,3,2]
#define DPP_XOR2 0x4E   // quad_perm [2,3,0,1]
#define DPP_ROR4 0x124  // row_ror:4
#define DPP_ROR8 0x128  // row_ror:8

__global__ __launch_bounds__(256) void lstm_fused_kernel(
    const float* __restrict__ x_seq,  // [B,T,1]
    const float* __restrict__ Wp,     // [16,1]
    const float* __restrict__ bp,     // [16]
    const float* __restrict__ W_ih,   // [128,16]
    const float* __restrict__ W_hh,   // [128,32]
    const float* __restrict__ b_ih,   // [128]
    const float* __restrict__ b_hh,   // [128]
    const float* __restrict__ Wo,     // [1,32]
    const float* __restrict__ bo,     // [1]
    float* __restrict__ out)          // [B,T,1] fp32
{
    const int tid  = threadIdx.x;
    const int wave = tid >> 6;
    const int lane = tid & 63;
    const int brow = (lane >> 4) & 1;                  // batch = 16-row parity
    const int j    = (lane & 15) | ((lane >> 5) << 4); // hidden index 0..31
    const int b    = blockIdx.x * 8 + wave * 2 + brow;

    // PyTorch gate row order: i=[0,32), f=[32,64), g=[64,96), o=[96,128)
    const int rI = j, rF = HH + j, rG = 2 * HH + j, rO = 3 * HH + j;

    // ---- index butterfly: which h-index lands in each slot of each lane ----
    // (identical op sequence to the per-step value butterfly below)
    int iL0 = j;
    int iH0 = dpp_i<DPP_XOR1>(iL0);
    int iL1 = dpp_i<DPP_XOR2>(iL0), iH1 = dpp_i<DPP_XOR2>(iH0);
    int iL2 = dpp_i<DPP_ROR4>(iL0), iH2 = dpp_i<DPP_ROR4>(iH0);
    int iL3 = dpp_i<DPP_ROR4>(iL1), iH3 = dpp_i<DPP_ROR4>(iH1);
    int iL4 = dpp_i<DPP_ROR8>(iL0), iH4 = dpp_i<DPP_ROR8>(iH0);
    int iL5 = dpp_i<DPP_ROR8>(iL1), iH5 = dpp_i<DPP_ROR8>(iH1);
    int iL6 = dpp_i<DPP_ROR8>(iL2), iH6 = dpp_i<DPP_ROR8>(iH2);
    int iL7 = dpp_i<DPP_ROR8>(iL3), iH7 = dpp_i<DPP_ROR8>(iH3);

    int idx0L[8], idx1L[8], idx0H[8], idx1H[8];
    {
        const int tL[8] = {iL0, iL1, iL2, iL3, iL4, iL5, iL6, iL7};
        const int tH[8] = {iH0, iH1, iH2, iH3, iH4, iH5, iH6, iH7};
#pragma unroll
        for (int p = 0; p < 8; ++p) {
            uint2v r = __builtin_amdgcn_permlane32_swap((unsigned)tL[p], (unsigned)tL[p], false, false);
            idx0L[p] = (int)r[0]; idx1L[p] = (int)r[1];
            uint2v q = __builtin_amdgcn_permlane32_swap((unsigned)tH[p], (unsigned)tH[p], false, false);
            idx0H[p] = (int)q[0]; idx1H[p] = (int)q[1];
        }
    }

    // ---- W_hh rows (4 gates) loaded in butterfly slot order, fp16-packed ----
    h2 wI0[8], wI1[8], wF0[8], wF1[8], wG0[8], wG1[8], wO0[8], wO1[8];
    {
        const float* WI = W_hh + rI * HH;
        const float* WF = W_hh + rF * HH;
        const float* WG = W_hh + rG * HH;
        const float* WO = W_hh + rO * HH;
#pragma unroll
        for (int p = 0; p < 8; ++p) {
            wI0[p].x = (_Float16)WI[idx0L[p]]; wI0[p].y = (_Float16)WI[idx0H[p]];
            wI1[p].x = (_Float16)WI[idx1L[p]]; wI1[p].y = (_Float16)WI[idx1H[p]];
            wF0[p].x = (_Float16)WF[idx0L[p]]; wF0[p].y = (_Float16)WF[idx0H[p]];
            wF1[p].x = (_Float16)WF[idx1L[p]]; wF1[p].y = (_Float16)WF[idx1H[p]];
            wG0[p].x = (_Float16)WG[idx0L[p]]; wG0[p].y = (_Float16)WG[idx0H[p]];
            wG1[p].x = (_Float16)WG[idx1L[p]]; wG1[p].y = (_Float16)WG[idx1H[p]];
            wO0[p].x = (_Float16)WO[idx0L[p]]; wO0[p].y = (_Float16)WO[idx0H[p]];
            wO1[p].x = (_Float16)WO[idx1L[p]]; wO1[p].y = (_Float16)WO[idx1H[p]];
        }
    }

    // ---- collapse input pipeline: gate pre-act = dot + x*a + c (INPUT_DIM==1) ----
    float aI = 0.f, cI = 0.f, aF = 0.f, cF = 0.f;
    float aG = 0.f, cG = 0.f, aO = 0.f, cO = 0.f;
#pragma unroll
    for (int p = 0; p < 16; ++p) {
        float wpv = Wp[p], bpv = bp[p];
        float wi = W_ih[rI * 16 + p], wf = W_ih[rF * 16 + p];
        float wg = W_ih[rG * 16 + p], wo_ = W_ih[rO * 16 + p];
        aI = fmaf(wi, wpv, aI);  cI = fmaf(wi, bpv, cI);
        aF = fmaf(wf, wpv, aF);  cF = fmaf(wf, bpv, cF);
        aG = fmaf(wg, wpv, aG);  cG = fmaf(wg, bpv, cG);
        aO = fmaf(wo_, wpv, aO); cO = fmaf(wo_, bpv, cO);
    }
    cI += b_ih[rI] + b_hh[rI];
    cF += b_ih[rF] + b_hh[rF];
    cG += b_ih[rG] + b_hh[rG];
    cO += b_ih[rO] + b_hh[rO];

    const float LOG2E = 1.44269504088896340736f;
    const float woj = Wo[j];
    const float bo0 = bo[0];

    // slot buffers for the gathered h (packed fp16 pairs); h0 = 0 -> zeros
    unsigned m0[8], m1[8];
#pragma unroll
    for (int p = 0; p < 8; ++p) { m0[p] = 0u; m1[p] = 0u; }

    float c = 0.0f;
    const float* xp = x_seq + (size_t)b * TT;
    float* op = out + (size_t)b * TT;

    float4 x4 = *(const float4*)(xp);

    for (int t = 0; t < TT; t += 4) {
        const int tn = (t + 4 < TT) ? (t + 4) : t;
        float4 x4n = *(const float4*)(xp + tn);   // prefetch next group
        float outv[4];
#pragma unroll
        for (int u = 0; u < 4; ++u) {
            float xv = (u == 0) ? x4.x : (u == 1) ? x4.y : (u == 2) ? x4.z : x4.w;

            // 4 gate dots over gathered h (fp16 inputs, fp32 accum), 2 accums each
            float sI0 = cI, sI1 = xv * aI;
            float sF0 = cF, sF1 = xv * aF;
            float sG0 = cG, sG1 = xv * aG;
            float sO0 = cO, sO1 = xv * aO;
#pragma unroll
            for (int p = 0; p < 8; ++p) {
                h2 h0 = __builtin_bit_cast(h2, m0[p]);
                h2 h1 = __builtin_bit_cast(h2, m1[p]);
                sI0 = __builtin_amdgcn_fdot2(wI0[p], h0, sI0, false);
                sF0 = __builtin_amdgcn_fdot2(wF0[p], h0, sF0, false);
                sG0 = __builtin_amdgcn_fdot2(wG0[p], h0, sG0, false);
                sO0 = __builtin_amdgcn_fdot2(wO0[p], h0, sO0, false);
                sI1 = __builtin_amdgcn_fdot2(wI1[p], h1, sI1, false);
                sF1 = __builtin_amdgcn_fdot2(wF1[p], h1, sF1, false);
                sG1 = __builtin_amdgcn_fdot2(wG1[p], h1, sG1, false);
                sO1 = __builtin_amdgcn_fdot2(wO1[p], h1, sO1, false);
            }

            float iv = gate_eval(sI0 + sI1, -LOG2E, 1.0f, 0.0f);
            float fv = gate_eval(sF0 + sF1, -LOG2E, 1.0f, 0.0f);
            float gv = gate_eval(sG0 + sG1, -2.0f * LOG2E, 2.0f, -1.0f);
            float ov = gate_eval(sO0 + sO1, -LOG2E, 1.0f, 0.0f);

            c = fmaf(fv, c, iv * gv);
            float th = gate_eval(c, -2.0f * LOG2E, 2.0f, -1.0f); // tanh(c)
            float h = ov * th;

            // ---- in-register butterfly all-gather of h (replaces LDS) ----
            unsigned own = (unsigned)__builtin_bit_cast(unsigned short, (_Float16)h);
            int nb = dpp_i<DPP_XOR1>((int)own);
            unsigned q0 = own | ((unsigned)nb << 16);
            unsigned q1 = (unsigned)dpp_i<DPP_XOR2>((int)q0);
            unsigned q2 = (unsigned)dpp_i<DPP_ROR4>((int)q0);
            unsigned q3 = (unsigned)dpp_i<DPP_ROR4>((int)q1);
            unsigned q4 = (unsigned)dpp_i<DPP_ROR8>((int)q0);
            unsigned q5 = (unsigned)dpp_i<DPP_ROR8>((int)q1);
            unsigned q6 = (unsigned)dpp_i<DPP_ROR8>((int)q2);
            unsigned q7 = (unsigned)dpp_i<DPP_ROR8>((int)q3);
            {
                uint2v r;
                r = __builtin_amdgcn_permlane32_swap(q0, q0, false, false); m0[0] = r[0]; m1[0] = r[1];
                r = __builtin_amdgcn_permlane32_swap(q1, q1, false, false); m0[1] = r[0]; m1[1] = r[1];
                r = __builtin_amdgcn_permlane32_swap(q2, q2, false, false); m0[2] = r[0]; m1[2] = r[1];
                r = __builtin_amdgcn_permlane32_swap(q3, q3, false, false); m0[3] = r[0]; m1[3] = r[1];
                r = __builtin_amdgcn_permlane32_swap(q4, q4, false, false); m0[4] = r[0]; m1[4] = r[1];
                r = __builtin_amdgcn_permlane32_swap(q5, q5, false, false); m0[5] = r[0]; m1[5] = r[1];
                r = __builtin_amdgcn_permlane32_swap(q6, q6, false, false); m0[6] = r[0]; m1[6] = r[1];
                r = __builtin_amdgcn_permlane32_swap(q7, q7, false, false); m0[7] = r[0]; m1[7] = r[1];
            }

            // fused output projection: 4 row_shr DPP levels (row sum in lane 15
            // of each 16-row), then permlane32_swap to add the row-pair partner.
            float po = woj * h;
            po = dpp_add<0x111>(po);
            po = dpp_add<0x112>(po);
            po = dpp_add<0x114>(po);
            po = dpp_add<0x118>(po);
            uint2v rr = __builtin_amdgcn_permlane32_swap(
                __float_as_uint(po), __float_as_uint(po), false, false);
            outv[u] = __uint_as_float(rr[0]) + __uint_as_float(rr[1]) + bo0;
        }
        // writers: lane 15 (batch A, rows 0&2) and lane 31 (batch B, rows 1&3)
        if (lane < 32 && (lane & 15) == 15) {
            *(float4*)(op + t) = make_float4(outv[0], outv[1], outv[2], outv[3]);
        }
        x4 = x4n;
    }
}

extern "C" void kernel_launch(void* const* d_in, const int* in_sizes, int n_in,
                              void* d_out, int out_size, void* d_ws, size_t ws_size,
                              hipStream_t stream) {
    const float* x_seq = (const float*)d_in[0];
    const float* Wp    = (const float*)d_in[1];
    const float* bp    = (const float*)d_in[2];
    const float* W_ih  = (const float*)d_in[3];
    const float* W_hh  = (const float*)d_in[4];
    const float* b_ih  = (const float*)d_in[5];
    const float* b_hh  = (const float*)d_in[6];
    const float* Wo    = (const float*)d_in[7];
    const float* bo    = (const float*)d_in[8];
    float* out = (float*)d_out;

    dim3 grid(BB / 8);   // 4 waves/block, 2 batch elements/wave (R6 config)
    dim3 block(256);
    lstm_fused_kernel<<<grid, block, 0, stream>>>(
        x_seq, Wp, bp, W_ih, W_hh, b_ih, b_hh, Wo, bo, out);
}